// Round 1
// baseline (916.458 us; speedup 1.0000x reference)
//
#include <hip/hip_runtime.h>
#include <math.h>

#define NV 128         // vector length (complex) = 8*8*2
#define NTRI 8256      // lower-tri entries of 128x128
#define KAP 0.276f
#define MAXIT 20

__device__ __forceinline__ float2 cadd(float2 a, float2 b){ return make_float2(a.x+b.x, a.y+b.y); }
__device__ __forceinline__ float2 csub(float2 a, float2 b){ return make_float2(a.x-b.x, a.y-b.y); }
__device__ __forceinline__ float2 cmul(float2 a, float2 b){ return make_float2(a.x*b.x - a.y*b.y, a.x*b.y + a.y*b.x); }
__device__ __forceinline__ float2 cmulc(float2 a, float2 b){ // conj(a)*b
  return make_float2(a.x*b.x + a.y*b.y, a.x*b.y - a.y*b.x); }
__device__ __forceinline__ float2 cmac(float2 acc, float2 a, float2 b){ // acc += a*b
  acc.x = fmaf(a.x, b.x, fmaf(-a.y, b.y, acc.x));
  acc.y = fmaf(a.x, b.y, fmaf( a.y, b.x, acc.y));
  return acc; }
__device__ __forceinline__ float2 cmacc(float2 acc, float2 a, float2 b){ // acc += conj(a)*b
  acc.x = fmaf(a.x, b.x, fmaf( a.y, b.y, acc.x));
  acc.y = fmaf(a.x, b.y, fmaf(-a.y, b.x, acc.y));
  return acc; }
__device__ __forceinline__ float2 cdiv(float2 n, float2 d){
  float s = 1.0f / fmaf(d.x, d.x, d.y*d.y);
  return make_float2((n.x*d.x + n.y*d.y)*s, (n.y*d.x - n.x*d.y)*s); }

// Wilson-Dirac hop. EF = coefficient sign of G on the FORWARD hop:
//   D    : fwd (I - G), bwd (I + G)  -> EF = -1
//   Ddag : fwd (I + G), bwd (I - G)  -> EF = +1
template<int EF>
__device__ __forceinline__ void dirac(const float2* __restrict__ U,
                                      const float2* __restrict__ vin,
                                      float2* __restrict__ vout, int t)
{
  if (t < NV) {
    const int s = t & 1, site = t >> 1;
    const int yi = site & 7, xi = site >> 3;
    const int xp = (xi+1)&7, xm = (xi-1)&7, yp = (yi+1)&7, ym = (yi-1)&7;
    float2 acc;
    // mu = 0 : sigma_x ; (I + e*sx) comp s = f_s + e*f_{1-s}
    {
      const int bf = (xp<<4) + (yi<<1);
      float2 fs = vin[bf + s], fo = vin[bf + (s^1)];
      float2 cf = (EF > 0) ? cadd(fs, fo) : csub(fs, fo);
      acc = cmul(U[(xi<<3)+yi], cf);
      const int bb = (xm<<4) + (yi<<1);
      float2 bs = vin[bb + s], bo = vin[bb + (s^1)];
      float2 cb = (EF > 0) ? csub(bs, bo) : cadd(bs, bo);
      acc = cadd(acc, cmulc(U[(xm<<3)+yi], cb));
    }
    // mu = 1 : sigma_y ; (I + e*sy) comp s = f_s + (e*tg)*i*f_{1-s}, tg = s?+1:-1
    {
      const float tg = s ? 1.0f : -1.0f;
      const float gf = (float)EF * tg;
      const int bf = (xi<<4) + (yp<<1);
      float2 fs = vin[bf + s], fo = vin[bf + (s^1)];
      float2 cf = make_float2(fmaf(-gf, fo.y, fs.x), fmaf(gf, fo.x, fs.y));
      acc = cadd(acc, cmul(U[64 + (xi<<3)+yi], cf));
      const float gb = -gf;
      const int bb = (xi<<4) + (ym<<1);
      float2 bs = vin[bb + s], bo = vin[bb + (s^1)];
      float2 cb = make_float2(fmaf(-gb, bo.y, bs.x), fmaf(gb, bo.x, bs.y));
      acc = cadd(acc, cmulc(U[64 + (xi<<3)+ym], cb));
    }
    float2 v0 = vin[t];
    vout[t] = make_float2(fmaf(-KAP, acc.x, v0.x), fmaf(-KAP, acc.y, v0.y));
  }
  __syncthreads();
}

// z = L^H (L v).  256 threads: row/col = t&127, parity half h = t>>7.
__device__ void precond(const float2* __restrict__ Lc, const float2* __restrict__ vin,
                        float2* __restrict__ wv, float2* __restrict__ vout,
                        float2* __restrict__ part, int t)
{
  const int r = t & 127, h = t >> 7;
  // pass 1: w_r = sum_j L[r][j] v[j]; parity split over j -> vin[j] wave-uniform (broadcast)
  {
    float2 acc = make_float2(0.f, 0.f);
    const int base = (r*(r+1)) >> 1;
    const int c = r + 1;
    for (int j = h; j < c; j += 2)
      acc = cmac(acc, Lc[base + j], vin[j]);
    part[t] = acc;
  }
  __syncthreads();
  if (t < NV) wv[t] = cadd(part[t], part[t + 128]);
  __syncthreads();
  // pass 2: z_r = sum_{i>=r} conj(L[i][r]) w[i]; uniform predicated sweep over rows i
  //         -> w[i] broadcast, L row-slice contiguous across lanes (conflict-free)
  {
    float2 acc = make_float2(0.f, 0.f);
    int addr = h + r;          // tri(h) + r  (tri(0)=0, tri(1)=1)
    #pragma unroll 4
    for (int i = h; i < NV; i += 2) {
      if (i >= r) acc = cmacc(acc, Lc[addr], wv[i]);
      addr += (i << 1) + 3;    // tri(i+2) - tri(i)
    }
    part[t] = acc;
  }
  __syncthreads();
  if (t < NV) vout[t] = cadd(part[t], part[t + 128]);
  __syncthreads();
}

__device__ float2 block_dot(const float2* __restrict__ a, const float2* __restrict__ c,
                            float2* __restrict__ scal, int t)
{
  float2 v = make_float2(0.f, 0.f);
  if (t < NV) v = cmacc(v, a[t], c[t]);   // conj(a)*c
  #pragma unroll
  for (int off = 32; off > 0; off >>= 1) {
    v.x += __shfl_down(v.x, off, 64);
    v.y += __shfl_down(v.y, off, 64);
  }
  if ((t & 63) == 0) scal[t >> 6] = v;
  __syncthreads();
  float2 res = cadd(scal[0], scal[1]);    // waves 2,3 contribute zero
  __syncthreads();
  return res;
}

extern "C" __global__ void __launch_bounds__(256, 2)
cg_loss_kernel(const float* __restrict__ nre, const float* __restrict__ nim,
               const float* __restrict__ theta, const float* __restrict__ bin,
               float* __restrict__ out, float invB)
{
  __shared__ float2 Lc[NTRI];                       // 66048 B packed lower-tri, interleaved re/im
  __shared__ float2 Uc[128];                        // U[mu][xi][yi]
  __shared__ float2 bv[NV], xv[NV], rv[NV], pv[NV], zv[NV], Apv[NV], tv[NV], wv[NV];
  __shared__ float2 part[256];
  __shared__ float2 scal[8];

  const int t = threadIdx.x;
  const long long b = blockIdx.x;

  // ---- stage L: coalesced float4 reads, interleave re/im into LDS ----
  {
    const float4* re4 = (const float4*)(nre + b * NTRI);
    const float4* im4 = (const float4*)(nim + b * NTRI);
    float4* Lc4 = (float4*)Lc;
    for (int k = t; k < NTRI/4; k += 256) {
      float4 r4 = re4[k], i4 = im4[k];
      Lc4[2*k]   = make_float4(r4.x, i4.x, r4.y, i4.y);
      Lc4[2*k+1] = make_float4(r4.z, i4.z, r4.w, i4.w);
    }
  }
  if (t < NV) {
    float th = theta[b * 128 + t];
    float sn, cs;
    sincosf(th, &sn, &cs);
    Uc[t] = make_float2(cs, sn);                    // exp(i*theta)
    float bb = bin[b * 128 + t];
    bv[t] = make_float2(bb, 0.f);
    xv[t] = make_float2(0.f, 0.f);
    rv[t] = make_float2(bb, 0.f);                   // r = b - A(0)
  }
  __syncthreads();

  precond(Lc, rv, wv, zv, part, t);                 // z = M r
  if (t < NV) pv[t] = zv[t];
  __syncthreads();
  float2 rz = block_dot(rv, zv, scal, t);

  for (int it = 0; it < MAXIT; ++it) {
    dirac<-1>(Uc, pv, tv, t);                       // t1 = D p
    dirac<+1>(Uc, tv, Apv, t);                      // Ap = Ddag t1
    float2 pAp = block_dot(pv, Apv, scal, t);
    float2 alpha = cdiv(rz, pAp);
    if (t < NV) {
      xv[t] = cmac(xv[t], alpha, pv[t]);            // x += alpha p
      rv[t] = csub(rv[t], cmul(alpha, Apv[t]));     // r -= alpha Ap
    }
    __syncthreads();
    precond(Lc, rv, wv, zv, part, t);               // z = M r
    float2 rz2 = block_dot(rv, zv, scal, t);
    float2 beta = cdiv(rz2, rz);
    if (t < NV) pv[t] = cmac(zv[t], beta, pv[t]);   // p = z + beta p
    rz = rz2;
    __syncthreads();
  }

  // res = A x - b ; rn = ||res||
  dirac<-1>(Uc, xv, tv, t);
  dirac<+1>(Uc, tv, Apv, t);
  float v = 0.f;
  if (t < NV) {
    float2 d = csub(Apv[t], bv[t]);
    v = fmaf(d.x, d.x, d.y * d.y);
  }
  #pragma unroll
  for (int off = 32; off > 0; off >>= 1) v += __shfl_down(v, off, 64);
  if ((t & 63) == 0) scal[t >> 6].x = v;
  __syncthreads();
  if (t == 0) {
    float rn = sqrtf(scal[0].x + scal[1].x);
    atomicAdd(out, rn * invB);
  }
}

extern "C" void kernel_launch(void* const* d_in, const int* in_sizes, int n_in,
                              void* d_out, int out_size, void* d_ws, size_t ws_size,
                              hipStream_t stream)
{
  const float* nre   = (const float*)d_in[0];
  const float* nim   = (const float*)d_in[1];
  const float* theta = (const float*)d_in[2];
  const float* bin   = (const float*)d_in[3];
  float* out = (float*)d_out;
  const int B = in_sizes[0] / NTRI;   // 2048

  hipMemsetAsync(out, 0, sizeof(float), stream);
  cg_loss_kernel<<<B, 256, 0, stream>>>(nre, nim, theta, bin, out, 1.0f / (float)B);
}

// Round 2
// 707.121 us; speedup vs baseline: 1.2960x; 1.2960x over previous
//
#include <hip/hip_runtime.h>
#include <math.h>

#define NV 128         // vector length (complex) = 8*8*2
#define NTRI 8256      // lower-tri entries of 128x128
#define KAP 0.276f
#define MAXIT 20
#define TPB 512        // 8 waves/block; LDS ~79.4 KB -> 2 blocks/CU -> 16 waves/CU

__device__ __forceinline__ float2 cadd(float2 a, float2 b){ return make_float2(a.x+b.x, a.y+b.y); }
__device__ __forceinline__ float2 csub(float2 a, float2 b){ return make_float2(a.x-b.x, a.y-b.y); }
__device__ __forceinline__ float2 cmul(float2 a, float2 b){ return make_float2(a.x*b.x - a.y*b.y, a.x*b.y + a.y*b.x); }
__device__ __forceinline__ float2 cmulc(float2 a, float2 b){ // conj(a)*b
  return make_float2(a.x*b.x + a.y*b.y, a.x*b.y - a.y*b.x); }
__device__ __forceinline__ float2 cmac(float2 acc, float2 a, float2 b){ // acc += a*b
  acc.x = fmaf(a.x, b.x, fmaf(-a.y, b.y, acc.x));
  acc.y = fmaf(a.x, b.y, fmaf( a.y, b.x, acc.y));
  return acc; }
__device__ __forceinline__ float2 cmacc(float2 acc, float2 a, float2 b){ // acc += conj(a)*b
  acc.x = fmaf(a.x, b.x, fmaf( a.y, b.y, acc.x));
  acc.y = fmaf(a.x, b.y, fmaf(-a.y, b.x, acc.y));
  return acc; }
__device__ __forceinline__ float2 cdiv(float2 n, float2 d){
  float s = 1.0f / fmaf(d.x, d.x, d.y*d.y);
  return make_float2((n.x*d.x + n.y*d.y)*s, (n.y*d.x - n.x*d.y)*s); }

// Wilson-Dirac hop. EF = coefficient sign of G on the FORWARD hop:
//   D    : fwd (I - G), bwd (I + G)  -> EF = -1
//   Ddag : fwd (I + G), bwd (I - G)  -> EF = +1
template<int EF>
__device__ __forceinline__ void dirac(const float2* __restrict__ U,
                                      const float2* __restrict__ vin,
                                      float2* __restrict__ vout, int t)
{
  if (t < NV) {
    const int s = t & 1, site = t >> 1;
    const int yi = site & 7, xi = site >> 3;
    const int xp = (xi+1)&7, xm = (xi-1)&7, yp = (yi+1)&7, ym = (yi-1)&7;
    float2 acc;
    // mu = 0 : sigma_x ; (I + e*sx) comp s = f_s + e*f_{1-s}
    {
      const int bf = (xp<<4) + (yi<<1);
      float2 fs = vin[bf + s], fo = vin[bf + (s^1)];
      float2 cf = (EF > 0) ? cadd(fs, fo) : csub(fs, fo);
      acc = cmul(U[(xi<<3)+yi], cf);
      const int bb = (xm<<4) + (yi<<1);
      float2 bs = vin[bb + s], bo = vin[bb + (s^1)];
      float2 cb = (EF > 0) ? csub(bs, bo) : cadd(bs, bo);
      acc = cadd(acc, cmulc(U[(xm<<3)+yi], cb));
    }
    // mu = 1 : sigma_y ; (I + e*sy) comp s = f_s + (e*tg)*i*f_{1-s}, tg = s?+1:-1
    {
      const float tg = s ? 1.0f : -1.0f;
      const float gf = (float)EF * tg;
      const int bf = (xi<<4) + (yp<<1);
      float2 fs = vin[bf + s], fo = vin[bf + (s^1)];
      float2 cf = make_float2(fmaf(-gf, fo.y, fs.x), fmaf(gf, fo.x, fs.y));
      acc = cadd(acc, cmul(U[64 + (xi<<3)+yi], cf));
      const float gb = -gf;
      const int bb = (xi<<4) + (ym<<1);
      float2 bs = vin[bb + s], bo = vin[bb + (s^1)];
      float2 cb = make_float2(fmaf(-gb, bo.y, bs.x), fmaf(gb, bo.x, bs.y));
      acc = cadd(acc, cmulc(U[64 + (xi<<3)+ym], cb));
    }
    float2 v0 = vin[t];
    vout[t] = make_float2(fmaf(-KAP, acc.x, v0.x), fmaf(-KAP, acc.y, v0.y));
  }
  __syncthreads();
}

// z = L^H (L v).  512 threads: row/col r = t&127, quarter q = t>>7 (0..3).
// Pass 1: per-lane row base (scattered b64, mild conflicts), vin[j] broadcast.
// Pass 2: contiguous across lanes (conflict-free), wv[i] broadcast.
// Wave-uniform trimming: pass 1 ends at r|63; pass 2 starts at (r&64)+q.
// Two accumulators break the fmaf dependency chain.
__device__ void precond(const float2* __restrict__ Lc, const float2* __restrict__ vin,
                        float2* __restrict__ wv, float2* __restrict__ vout,
                        float2* __restrict__ part, int t)
{
  const int r = t & 127, q = t >> 7;
  // pass 1: w_r = sum_{j<=r} L[r][j] v[j]
  {
    float2 a0 = make_float2(0.f, 0.f), a1 = make_float2(0.f, 0.f);
    const int base = (r*(r+1)) >> 1;
    const int jend = r | 63;                 // wave-uniform (63 or 127)
    for (int j = q; j <= jend; j += 8) {
      if (j <= r)      a0 = cmac(a0, Lc[base + j], vin[j]);
      const int j2 = j + 4;
      if (j2 <= r)     a1 = cmac(a1, Lc[base + j2], vin[j2]);
    }
    part[t] = cadd(a0, a1);
  }
  __syncthreads();
  if (t < NV) wv[t] = cadd(cadd(part[t], part[t+128]), cadd(part[t+256], part[t+384]));
  __syncthreads();
  // pass 2: z_r = sum_{i>=r} conj(L[i][r]) w[i]
  {
    float2 a0 = make_float2(0.f, 0.f), a1 = make_float2(0.f, 0.f);
    int i = (r & 64) + q;                    // wave-uniform start
    int addr = ((i*(i+1)) >> 1) + r;         // tri(i) + r
    int d = (i << 2) + 10;                   // tri(i+4) - tri(i)
    for (; i < NV; i += 8) {
      if (i >= r)        a0 = cmacc(a0, Lc[addr], wv[i]);
      const int i2 = i + 4;
      if (i2 >= r)       a1 = cmacc(a1, Lc[addr + d], wv[i2]);
      addr += (d << 1) + 16;                 // tri(i+8) - tri(i)
      d += 32;
    }
    part[t] = cadd(a0, a1);
  }
  __syncthreads();
  if (t < NV) vout[t] = cadd(cadd(part[t], part[t+128]), cadd(part[t+256], part[t+384]));
  // no trailing sync: vout[t] is only re-read by thread t before the next barrier
}

__device__ float2 block_dot(const float2* __restrict__ a, const float2* __restrict__ c,
                            float2* __restrict__ scal, int t)
{
  float2 v = make_float2(0.f, 0.f);
  if (t < NV) v = cmacc(v, a[t], c[t]);   // conj(a)*c
  #pragma unroll
  for (int off = 32; off > 0; off >>= 1) {
    v.x += __shfl_down(v.x, off, 64);
    v.y += __shfl_down(v.y, off, 64);
  }
  if ((t & 63) == 0) scal[t >> 6] = v;
  __syncthreads();
  float2 res = cadd(scal[0], scal[1]);    // waves 2..7 contribute zero
  __syncthreads();                        // WAR guard on scal reuse
  return res;
}

extern "C" __global__ void __launch_bounds__(TPB, 4)
cg_loss_kernel(const float* __restrict__ nre, const float* __restrict__ nim,
               const float* __restrict__ theta, const float* __restrict__ bin,
               float* __restrict__ out, float invB)
{
  __shared__ float2 Lc[NTRI];                       // 66048 B packed lower-tri, interleaved re/im
  __shared__ float2 Uc[128];                        // U[mu][xi][yi]
  __shared__ float2 bv[NV], xv[NV], rv[NV], pv[NV], zv[NV], Apv[NV], tv[NV], wv[NV];
  __shared__ float2 part[TPB];
  __shared__ float2 scal[8];

  const int t = threadIdx.x;
  const long long b = blockIdx.x;

  // ---- stage L: coalesced float4 reads, interleave re/im into LDS ----
  {
    const float4* re4 = (const float4*)(nre + b * NTRI);
    const float4* im4 = (const float4*)(nim + b * NTRI);
    float4* Lc4 = (float4*)Lc;
    for (int k = t; k < NTRI/4; k += TPB) {
      float4 r4 = re4[k], i4 = im4[k];
      Lc4[2*k]   = make_float4(r4.x, i4.x, r4.y, i4.y);
      Lc4[2*k+1] = make_float4(r4.z, i4.z, r4.w, i4.w);
    }
  }
  if (t < NV) {
    float th = theta[b * 128 + t];
    float sn, cs;
    sincosf(th, &sn, &cs);
    Uc[t] = make_float2(cs, sn);                    // exp(i*theta)
    float bb = bin[b * 128 + t];
    bv[t] = make_float2(bb, 0.f);
    xv[t] = make_float2(0.f, 0.f);
    rv[t] = make_float2(bb, 0.f);                   // r = b - A(0)
  }
  __syncthreads();

  precond(Lc, rv, wv, zv, part, t);                 // z = M r
  if (t < NV) pv[t] = zv[t];
  __syncthreads();
  float2 rz = block_dot(rv, zv, scal, t);

  for (int it = 0; it < MAXIT; ++it) {
    dirac<-1>(Uc, pv, tv, t);                       // t1 = D p
    dirac<+1>(Uc, tv, Apv, t);                      // Ap = Ddag t1
    float2 pAp = block_dot(pv, Apv, scal, t);
    float2 alpha = cdiv(rz, pAp);
    if (t < NV) {
      xv[t] = cmac(xv[t], alpha, pv[t]);            // x += alpha p
      rv[t] = csub(rv[t], cmul(alpha, Apv[t]));     // r -= alpha Ap
    }
    __syncthreads();
    precond(Lc, rv, wv, zv, part, t);               // z = M r
    float2 rz2 = block_dot(rv, zv, scal, t);
    float2 beta = cdiv(rz2, rz);
    if (t < NV) pv[t] = cmac(zv[t], beta, pv[t]);   // p = z + beta p
    rz = rz2;
    __syncthreads();
  }

  // res = A x - b ; rn = ||res||
  dirac<-1>(Uc, xv, tv, t);
  dirac<+1>(Uc, tv, Apv, t);
  float v = 0.f;
  if (t < NV) {
    float2 d = csub(Apv[t], bv[t]);
    v = fmaf(d.x, d.x, d.y * d.y);
  }
  #pragma unroll
  for (int off = 32; off > 0; off >>= 1) v += __shfl_down(v, off, 64);
  if ((t & 63) == 0) scal[t >> 6].x = v;
  __syncthreads();
  if (t == 0) {
    float rn = sqrtf(scal[0].x + scal[1].x);
    atomicAdd(out, rn * invB);
  }
}

extern "C" void kernel_launch(void* const* d_in, const int* in_sizes, int n_in,
                              void* d_out, int out_size, void* d_ws, size_t ws_size,
                              hipStream_t stream)
{
  const float* nre   = (const float*)d_in[0];
  const float* nim   = (const float*)d_in[1];
  const float* theta = (const float*)d_in[2];
  const float* bin   = (const float*)d_in[3];
  float* out = (float*)d_out;
  const int B = in_sizes[0] / NTRI;   // 2048

  hipMemsetAsync(out, 0, sizeof(float), stream);
  cg_loss_kernel<<<B, TPB, 0, stream>>>(nre, nim, theta, bin, out, 1.0f / (float)B);
}

// Round 3
// 675.479 us; speedup vs baseline: 1.3568x; 1.0468x over previous
//
#include <hip/hip_runtime.h>
#include <math.h>

#define NV 128         // vector length (complex) = 8*8*2
#define NTRI 8256      // lower-tri entries of 128x128
#define KAP 0.276f
#define MAXIT 20
#define TPB 512        // 8 waves/block; LDS ~80 KB -> 2 blocks/CU -> 16 waves/CU

__device__ __forceinline__ float2 cadd(float2 a, float2 b){ return make_float2(a.x+b.x, a.y+b.y); }
__device__ __forceinline__ float2 csub(float2 a, float2 b){ return make_float2(a.x-b.x, a.y-b.y); }
__device__ __forceinline__ float2 cmul(float2 a, float2 b){ return make_float2(a.x*b.x - a.y*b.y, a.x*b.y + a.y*b.x); }
__device__ __forceinline__ float2 cmulc(float2 a, float2 b){ // conj(a)*b
  return make_float2(a.x*b.x + a.y*b.y, a.x*b.y - a.y*b.x); }
__device__ __forceinline__ float2 cmac(float2 acc, float2 a, float2 b){ // acc += a*b
  acc.x = fmaf(a.x, b.x, fmaf(-a.y, b.y, acc.x));
  acc.y = fmaf(a.x, b.y, fmaf( a.y, b.x, acc.y));
  return acc; }
__device__ __forceinline__ float2 cmacc(float2 acc, float2 a, float2 b){ // acc += conj(a)*b
  acc.x = fmaf(a.x, b.x, fmaf( a.y, b.y, acc.x));
  acc.y = fmaf(a.x, b.y, fmaf(-a.y, b.x, acc.y));
  return acc; }
__device__ __forceinline__ float2 cdiv(float2 n, float2 d){
  float s = 1.0f / fmaf(d.x, d.x, d.y*d.y);
  return make_float2((n.x*d.x + n.y*d.y)*s, (n.y*d.x - n.x*d.y)*s); }

// Wilson-Dirac hop. EF = coefficient sign of G on the FORWARD hop:
//   D    : fwd (I - G), bwd (I + G)  -> EF = -1
//   Ddag : fwd (I + G), bwd (I - G)  -> EF = +1
template<int EF>
__device__ __forceinline__ void dirac(const float2* __restrict__ U,
                                      const float2* __restrict__ vin,
                                      float2* __restrict__ vout, int t)
{
  if (t < NV) {
    const int s = t & 1, site = t >> 1;
    const int yi = site & 7, xi = site >> 3;
    const int xp = (xi+1)&7, xm = (xi-1)&7, yp = (yi+1)&7, ym = (yi-1)&7;
    float2 acc;
    // mu = 0 : sigma_x ; (I + e*sx) comp s = f_s + e*f_{1-s}
    {
      const int bf = (xp<<4) + (yi<<1);
      float2 fs = vin[bf + s], fo = vin[bf + (s^1)];
      float2 cf = (EF > 0) ? cadd(fs, fo) : csub(fs, fo);
      acc = cmul(U[(xi<<3)+yi], cf);
      const int bb = (xm<<4) + (yi<<1);
      float2 bs = vin[bb + s], bo = vin[bb + (s^1)];
      float2 cb = (EF > 0) ? csub(bs, bo) : cadd(bs, bo);
      acc = cadd(acc, cmulc(U[(xm<<3)+yi], cb));
    }
    // mu = 1 : sigma_y ; (I + e*sy) comp s = f_s + (e*tg)*i*f_{1-s}, tg = s?+1:-1
    {
      const float tg = s ? 1.0f : -1.0f;
      const float gf = (float)EF * tg;
      const int bf = (xi<<4) + (yp<<1);
      float2 fs = vin[bf + s], fo = vin[bf + (s^1)];
      float2 cf = make_float2(fmaf(-gf, fo.y, fs.x), fmaf(gf, fo.x, fs.y));
      acc = cadd(acc, cmul(U[64 + (xi<<3)+yi], cf));
      const float gb = -gf;
      const int bb = (xi<<4) + (ym<<1);
      float2 bs = vin[bb + s], bo = vin[bb + (s^1)];
      float2 cb = make_float2(fmaf(-gb, bo.y, bs.x), fmaf(gb, bo.x, bs.y));
      acc = cadd(acc, cmulc(U[64 + (xi<<3)+ym], cb));
    }
    float2 v0 = vin[t];
    vout[t] = make_float2(fmaf(-KAP, acc.x, v0.x), fmaf(-KAP, acc.y, v0.y));
  }
  __syncthreads();
}

// z = L^H (L v).  512 threads: row/col r = t&127, quarter q = t>>7 (0..3).
// q and (r&64) are wave-uniform -> both passes fully unrolled per branch.
// Adjacent pairs (j, j+1) -> ds_read2_b64/b128-mergeable LDS traffic.
__device__ __forceinline__ void precond(const float2* __restrict__ Lc, const float2* __restrict__ vin,
                        float2* __restrict__ wv, float2* __restrict__ vout,
                        float2* __restrict__ part, int t)
{
  const int r = t & 127, q = t >> 7;
  const int J0 = q << 1;
  // ---- pass 1: w_r = sum_{j<=r} L[r][j] v[j] ----
  {
    float2 a0 = make_float2(0.f,0.f), a1 = make_float2(0.f,0.f);
    const int base = (r*(r+1)) >> 1;
    if (r < 64) {
      #pragma unroll
      for (int k = 0; k < 8; ++k) {
        const int J = J0 + 8*k;
        float2 L0 = Lc[base+J], L1 = Lc[base+J+1];
        float2 v0 = vin[J],     v1 = vin[J+1];
        if (J   <= r) a0 = cmac(a0, L0, v0);
        if (J+1 <= r) a1 = cmac(a1, L1, v1);
      }
    } else {
      #pragma unroll
      for (int k = 0; k < 8; ++k) {        // J+1 <= 63 < r : unconditional
        const int J = J0 + 8*k;
        a0 = cmac(a0, Lc[base+J],   vin[J]);
        a1 = cmac(a1, Lc[base+J+1], vin[J+1]);
      }
      #pragma unroll
      for (int k = 8; k < 16; ++k) {
        const int J = J0 + 8*k;
        float2 L0 = Lc[base+J], L1 = Lc[base+J+1];
        float2 v0 = vin[J],     v1 = vin[J+1];
        if (J   <= r) a0 = cmac(a0, L0, v0);
        if (J+1 <= r) a1 = cmac(a1, L1, v1);
      }
    }
    part[t] = cadd(a0, a1);
  }
  __syncthreads();
  if (t < NV) wv[t] = cadd(cadd(part[t], part[t+128]), cadd(part[t+256], part[t+384]));
  __syncthreads();
  // ---- pass 2: z_r = sum_{i>=r} conj(L[i][r]) w[i] ----
  {
    float2 a0 = make_float2(0.f,0.f), a1 = make_float2(0.f,0.f);
    if (r < 64) {
      #pragma unroll
      for (int k = 0; k < 16; ++k) {       // k>=8 -> i>=64>r : unconditional
        const int i = J0 + 8*k;
        const int ad = ((i*(i+1)) >> 1) + r;
        float2 L0 = Lc[ad], L1 = Lc[ad + i + 1];
        float2 w0 = wv[i],  w1 = wv[i+1];
        if (k >= 8 || i   >= r) a0 = cmacc(a0, L0, w0);
        if (k >= 8 || i+1 >= r) a1 = cmacc(a1, L1, w1);
      }
    } else {
      #pragma unroll
      for (int k = 0; k < 8; ++k) {
        const int i = 64 + J0 + 8*k;
        const int ad = ((i*(i+1)) >> 1) + r;
        float2 L0 = Lc[ad], L1 = Lc[ad + i + 1];
        float2 w0 = wv[i],  w1 = wv[i+1];
        if (i   >= r) a0 = cmacc(a0, L0, w0);
        if (i+1 >= r) a1 = cmacc(a1, L1, w1);
      }
    }
    part[t] = cadd(a0, a1);
  }
  __syncthreads();
  if (t < NV) vout[t] = cadd(cadd(part[t], part[t+128]), cadd(part[t+256], part[t+384]));
  // no trailing barrier: vout[t] only re-read by thread t before the next barrier
}

// conj(a).c reduced over t<128. Only waves 0,1 reduce/write; scal slot double-buffered.
__device__ __forceinline__ float2 block_dot(const float2* __restrict__ a, const float2* __restrict__ c,
                            float2* __restrict__ scal, int t, int slot)
{
  if (t < NV) {
    float2 v = cmacc(make_float2(0.f,0.f), a[t], c[t]);
    #pragma unroll
    for (int off = 32; off > 0; off >>= 1) {
      v.x += __shfl_down(v.x, off, 64);
      v.y += __shfl_down(v.y, off, 64);
    }
    if ((t & 63) == 0) scal[(slot<<1) + (t >> 6)] = v;
  }
  __syncthreads();
  return cadd(scal[slot<<1], scal[(slot<<1)+1]);
}

extern "C" __global__ void __launch_bounds__(TPB, 4)
cg_loss_kernel(const float* __restrict__ nre, const float* __restrict__ nim,
               const float* __restrict__ theta, const float* __restrict__ bin,
               float* __restrict__ out, float invB)
{
  __shared__ float2 Lc[NTRI];                       // 66048 B packed lower-tri, interleaved re/im
  __shared__ float2 Uc[128];                        // U[mu][xi][yi]
  __shared__ float2 bv[NV], xv[NV], rv[NV], pv[NV], zv[NV], Apv[NV], tv[NV], wv[NV];
  __shared__ float2 part[TPB];
  __shared__ float2 scal[8];

  const int t = threadIdx.x;
  const long long b = blockIdx.x;

  // ---- stage L: coalesced float4 reads, interleave re/im into LDS ----
  {
    const float4* re4 = (const float4*)(nre + b * NTRI);
    const float4* im4 = (const float4*)(nim + b * NTRI);
    float4* Lc4 = (float4*)Lc;
    for (int k = t; k < NTRI/4; k += TPB) {
      float4 r4 = re4[k], i4 = im4[k];
      Lc4[2*k]   = make_float4(r4.x, i4.x, r4.y, i4.y);
      Lc4[2*k+1] = make_float4(r4.z, i4.z, r4.w, i4.w);
    }
  }
  if (t < NV) {
    float th = theta[b * 128 + t];
    float sn, cs;
    sincosf(th, &sn, &cs);
    Uc[t] = make_float2(cs, sn);                    // exp(i*theta)
    float bb = bin[b * 128 + t];
    bv[t] = make_float2(bb, 0.f);
    xv[t] = make_float2(0.f, 0.f);
    rv[t] = make_float2(bb, 0.f);                   // r = b - A(0)
  }
  __syncthreads();

  precond(Lc, rv, wv, zv, part, t);                 // z = M r
  if (t < NV) pv[t] = zv[t];
  float2 rz = block_dot(rv, zv, scal, t, 0);        // internal barrier also publishes pv

  for (int it = 0; it < MAXIT; ++it) {
    dirac<-1>(Uc, pv, tv, t);                       // t1 = D p
    dirac<+1>(Uc, tv, Apv, t);                      // Ap = Ddag t1
    float2 pAp = block_dot(pv, Apv, scal, t, 1);    // operands own-thread-written
    if (t < NV) {
      float2 alpha = cdiv(rz, pAp);
      xv[t] = cmac(xv[t], alpha, pv[t]);            // x += alpha p
      rv[t] = csub(rv[t], cmul(alpha, Apv[t]));     // r -= alpha Ap
    }
    __syncthreads();                                // rv visible to pass 1
    precond(Lc, rv, wv, zv, part, t);               // z = M r
    float2 rz2 = block_dot(rv, zv, scal, t, 0);     // operands own-thread-written
    if (t < NV) {
      float2 beta = cdiv(rz2, rz);
      pv[t] = cmac(zv[t], beta, pv[t]);             // p = z + beta p
    }
    rz = rz2;
    __syncthreads();                                // pv visible to next dirac
  }

  // res = A x - b ; rn = ||res||
  dirac<-1>(Uc, xv, tv, t);
  dirac<+1>(Uc, tv, Apv, t);
  if (t < NV) {
    float2 d = csub(Apv[t], bv[t]);
    float v = fmaf(d.x, d.x, d.y * d.y);
    #pragma unroll
    for (int off = 32; off > 0; off >>= 1) v += __shfl_down(v, off, 64);
    if ((t & 63) == 0) scal[4 + (t >> 6)].x = v;
  }
  __syncthreads();
  if (t == 0) {
    float rn = sqrtf(scal[4].x + scal[5].x);
    atomicAdd(out, rn * invB);
  }
}

extern "C" void kernel_launch(void* const* d_in, const int* in_sizes, int n_in,
                              void* d_out, int out_size, void* d_ws, size_t ws_size,
                              hipStream_t stream)
{
  const float* nre   = (const float*)d_in[0];
  const float* nim   = (const float*)d_in[1];
  const float* theta = (const float*)d_in[2];
  const float* bin   = (const float*)d_in[3];
  float* out = (float*)d_out;
  const int B = in_sizes[0] / NTRI;   // 2048

  hipMemsetAsync(out, 0, sizeof(float), stream);
  cg_loss_kernel<<<B, TPB, 0, stream>>>(nre, nim, theta, bin, out, 1.0f / (float)B);
}